// Round 6
// baseline (177.021 us; speedup 1.0000x reference)
//
#include <hip/hip_runtime.h>

constexpr int Lc = 16;
constexpr int Cc = 16;
constexpr int Hc = 128;
constexpr int Wc = 256;
constexpr float DECAYc = 0.1f;
constexpr int HWc = Hc * Wc;

// float -> bf16 bits, round-to-nearest-even (inputs are finite normals).
__device__ inline unsigned short f2bf(float f) {
    unsigned int u = __float_as_uint(f);
    u += 0x7fffu + ((u >> 16) & 1u);
    return (unsigned short)(u >> 16);
}
// packed uint (bf16 pair) -> 2 floats
__device__ inline float2 bf2f2(unsigned int u) {
    return make_float2(__uint_as_float(u << 16),
                       __uint_as_float(u & 0xffff0000u));
}

constexpr int topbit(unsigned m) { int r = 0; while (m >>= 1) ++r; return r; }

// ---------------------------------------------------------------------------
// Kernel 1: transpose+convert img (L,C,H,W) f32 -> imgTb (L,H,W,C) bf16.
// (unchanged)
// ---------------------------------------------------------------------------
__global__ __launch_bounds__(256) void transpose_cvt_bf16(
    const float* __restrict__ img, unsigned short* __restrict__ imgTb)
{
    const int tid = threadIdx.x;
    const int h2 = tid & 1;
    const int wq = tid >> 1;             // 0..127
    const int kf  = blockIdx.x >> 5;     // 0..15
    const int px0 = (blockIdx.x & 31) * 1024;
    const float* __restrict__ srcb = img + (size_t)kf * Cc * HWc + (size_t)(8 * h2) * HWc;
#pragma unroll
    for (int rr = 0; rr < 8; ++rr) {
        const int px = px0 + rr * 128 + wq;
        float v[8];
#pragma unroll
        for (int c = 0; c < 8; ++c) v[c] = srcb[c * HWc + px];
        uint4 o;
        o.x = (unsigned int)f2bf(v[0]) | ((unsigned int)f2bf(v[1]) << 16);
        o.y = (unsigned int)f2bf(v[2]) | ((unsigned int)f2bf(v[3]) << 16);
        o.z = (unsigned int)f2bf(v[4]) | ((unsigned int)f2bf(v[5]) << 16);
        o.w = (unsigned int)f2bf(v[6]) | ((unsigned int)f2bf(v[7]) << 16);
        *(uint4*)(imgTb + ((size_t)kf * HWc + px) * Cc + 8 * h2) = o;
    }
}

// 8-channel FMA-accumulate of one 16B bf16 record slice.
__device__ __forceinline__ void accum8(float* a, uint4 v, float w) {
    const float2 f01 = bf2f2(v.x);
    const float2 f23 = bf2f2(v.y);
    const float2 f45 = bf2f2(v.z);
    const float2 f67 = bf2f2(v.w);
    a[0] += w * f01.x;  a[1] += w * f01.y;
    a[2] += w * f23.x;  a[3] += w * f23.y;
    a[4] += w * f45.x;  a[5] += w * f45.y;
    a[6] += w * f67.x;  a[7] += w * f67.y;
}

// ---------------------------------------------------------------------------
// One k-step, single merged batch: phase A computes MINIMAL address math
// (1 sub per axis via precomputed Px/Py and per-k Qx/Qy) for all active t
// and issues ALL gathers (<=16 uint4) back-to-back; phase B then does the
// wtab read + weight algebra + accumulate UNDER the memory wait (the
// compiler's staged vmcnt overlaps later loads with earlier consumes).
// Round 5 had 2 batches + a flow load-use stall per k -> 3 latency fences;
// this has 1.  x-wrap folded into &255 (bit-exact, validated round 2);
// the Px/Qx re-association changes ix by ~ulp, harmless by continuity of
// bilinear interpolation in ix (validated rounds 2-5, absmax 0.0625).
// ---------------------------------------------------------------------------
template <unsigned MASK>
__device__ __forceinline__ void k_step(
    int k, const unsigned short* __restrict__ bk, int half,
    const float* Px, const float* Py, float Qx, float Qy,
    const float* __restrict__ wtab, float (*acc)[8])
{
    uint4 ld [Lc][4];
    float wxs[Lc], wys[Lc];

    // A: addresses + issue all loads
#pragma unroll
    for (int t = 1; t < Lc; ++t) {
        if (!((MASK >> t) & 1u)) continue;
        if (t > k) {
            const float ix = Px[t] - Qx;
            const float iy = Py[t] - Qy;
            const float x0f = floorf(ix);
            const float y0f = floorf(iy);
            wxs[t] = ix - x0f;
            wys[t] = iy - y0f;
            const int x0 = (int)x0f;
            const int y0 = (int)y0f;
            const int x0r = x0 & (Wc - 1);
            const int x1r = (x0 + 1) & (Wc - 1);
            const int y0c = min(max(y0, 0), Hc - 1);
            const int y1c = min(max(y0 + 1, 0), Hc - 1);
            ld[t][0] = ((const uint4*)(bk + (size_t)(y0c * Wc + x0r) * Cc))[half];
            ld[t][1] = ((const uint4*)(bk + (size_t)(y0c * Wc + x1r) * Cc))[half];
            ld[t][2] = ((const uint4*)(bk + (size_t)(y1c * Wc + x0r) * Cc))[half];
            ld[t][3] = ((const uint4*)(bk + (size_t)(y1c * Wc + x1r) * Cc))[half];
        }
    }
    // B: weights + accumulate (runs under the vmcnt wait)
#pragma unroll
    for (int t = 1; t < Lc; ++t) {
        if (!((MASK >> t) & 1u)) continue;
        if (t > k) {
            const float wkt = wtab[t * Lc + k];
            const float wx = wxs[t], wy = wys[t];
            const float wb = wkt * wy;
            const float wa = wkt - wb;
            const float omx = 1.0f - wx;
            accum8(acc[t], ld[t][0], wa * omx);
            accum8(acc[t], ld[t][1], wa * wx);
            accum8(acc[t], ld[t][2], wb * omx);
            accum8(acc[t], ld[t][3], wb * wx);
        }
    }
}

// ---------------------------------------------------------------------------
// One t-quarter (MASK) for one (pixel, channel-half) lane.
// ---------------------------------------------------------------------------
template <unsigned MASK>
__device__ __forceinline__ void run_quarter(
    const unsigned short* __restrict__ imgTb,
    const float* __restrict__ cum_flow,
    const float* __restrict__ img,
    float* __restrict__ out,
    const float* wtab,
    int half, int pix, float base_x, float base_y)
{
    constexpr unsigned LOOPM = MASK & ~1u;   // t=0 never samples (k<t empty)

    // Px/Py: target-frame coordinate bases, one pair per owned t.
    float Px[Lc], Py[Lc];
#pragma unroll
    for (int t = 0; t < Lc; ++t) {
        if (!((LOOPM >> t) & 1u)) continue;
        const float ftx = cum_flow[(t * 2 + 0) * HWc + pix];
        const float fty = cum_flow[(t * 2 + 1) * HWc + pix];
        Px[t] = (base_x + 1.0f + ftx) * (Wc * 0.5f) - 0.5f;
        Py[t] = (base_y + 1.0f + fty) * (Hc * 0.5f) - 0.5f;
    }

    float acc[Lc][8];
#pragma unroll
    for (int t = 0; t < Lc; ++t) {
        if (!((MASK >> t) & 1u)) continue;
#pragma unroll
        for (int c = 0; c < 8; ++c) acc[t][c] = 0.f;
    }

    constexpr int KMAX = topbit(MASK);   // highest masked t; k in [0, KMAX)

    // Flow for k=0, prefetched; thereafter prefetch k+1 while computing k.
    float qfx = cum_flow[0 * HWc + pix];
    float qfy = cum_flow[1 * HWc + pix];

    for (int k = 0; k < KMAX; ++k) {
        const float Qx = qfx * (Wc * 0.5f);
        const float Qy = qfy * (Hc * 0.5f);
        // prefetch next k's flow (k+1 <= 15 always in-bounds: L=16 planes)
        qfx = cum_flow[((k + 1) * 2 + 0) * HWc + pix];
        qfy = cum_flow[((k + 1) * 2 + 1) * HWc + pix];
        const unsigned short* __restrict__ bk = imgTb + (size_t)k * HWc * Cc;
        k_step<LOOPM>(k, bk, half, Px, Py, Qx, Qy, wtab, acc);
    }

    // Epilogue: add exact fp32 identity sample (t==k, weight 1) and store.
#pragma unroll
    for (int t = 0; t < Lc; ++t) {
        if (!((MASK >> t) & 1u)) continue;
        const float* __restrict__ ip = img + ((size_t)t * Cc + 8 * half) * HWc + pix;
        float* __restrict__ op = out + ((size_t)t * Cc + 8 * half) * HWc + pix;
#pragma unroll
        for (int c = 0; c < 8; ++c)
            op[c * HWc] = acc[t][c] + ip[c * HWc];
    }
}

// ---------------------------------------------------------------------------
// Kernel 2: wave-level t-quartered HALF-layout accumulate (16B gathers),
// single-batch k-steps + flow register-prefetch.
// Block = 32 px x 2 ch-halves x 4 waves; wave id (tid>>6) picks a t-quarter
// {15,8,5,2} {14,9,6,1} {13,10,4,3} {12,11,7,0} (30 (k,t)-pairs each).
//  - 32-px block footprint = one 128B line per (t,c) plane (round-4 lesson);
//  - quarters share the block -> frames swept in k-lockstep (round-1/2
//    lesson);
//  - per k: ONE gather batch (<=16 uint4 in flight) and ZERO load-use
//    stalls at the loop head (round-5 post-mortem: ~90% of wave lifetime
//    was memory wait across 3 latency fences per k; now 1).
// 1024 blocks = 4/CU x 4 waves = 16 waves/CU cap; band = b&7 -> XCD.
// ---------------------------------------------------------------------------
__global__ __launch_bounds__(256, 4) void gridsample_bf16_h16b(
    const unsigned short* __restrict__ imgTb,  // (L, H, W, C) bf16
    const float* __restrict__ cum_flow,        // (L, 2, H, W)
    const float* __restrict__ mask,            // (L, L)
    const float* __restrict__ decay,           // (L, L)
    const float* __restrict__ img,             // (L, C, H, W) f32, identity
    float* __restrict__ out)                   // (L, C, H, W)
{
    __shared__ float wtab[Lc * Lc];
    const int tid = threadIdx.x;
    if (tid < Lc * Lc)
        wtab[tid] = mask[tid] * __expf(-DECAYc * decay[tid]);
    __syncthreads();

    const int half = tid & 1;            // channel half: 8*half .. 8*half+7
    const int px32 = (tid >> 1) & 31;    // pixel within block
    const int wv   = tid >> 6;           // wave id = t-quarter
    const int b    = blockIdx.x;         // 0..1023
    const int band = b & 7;              // XCD id under modulo dispatch
    const int sub  = b >> 3;             // 0..127 within band
    const int h = band * 16 + (sub >> 3);
    const int w = (sub & 7) * 32 + px32;
    const int pix = h * Wc + w;

    const float base_x = w * (2.0f / Wc) - 1.0f + 1.0f / Wc;
    const float base_y = h * (2.0f / Hc) - 1.0f + 1.0f / Hc;

    switch (wv) {
        case 0:  run_quarter<0x8124u>(imgTb, cum_flow, img, out, wtab, half, pix, base_x, base_y); break; // {15,8,5,2}
        case 1:  run_quarter<0x4242u>(imgTb, cum_flow, img, out, wtab, half, pix, base_x, base_y); break; // {14,9,6,1}
        case 2:  run_quarter<0x2418u>(imgTb, cum_flow, img, out, wtab, half, pix, base_x, base_y); break; // {13,10,4,3}
        default: run_quarter<0x1881u>(imgTb, cum_flow, img, out, wtab, half, pix, base_x, base_y); break; // {12,11,7,0}
    }
}

// ---------------------------------------------------------------------------
// Fallback (Round-1 kernel): used only if ws_size is too small.
// ---------------------------------------------------------------------------
__global__ __launch_bounds__(256) void gridsample_warp_acc(
    const float* __restrict__ img, const float* __restrict__ cum_flow,
    const float* __restrict__ mask, const float* __restrict__ decay,
    float* __restrict__ out)
{
    const int w = threadIdx.x, h = blockIdx.x, t = blockIdx.y;
    const int pix = h * Wc + w;
    const float base_x = w * (2.0f / Wc) - 1.0f + 1.0f / Wc;
    const float base_y = h * (2.0f / Hc) - 1.0f + 1.0f / Hc;
    const float fxt = cum_flow[(t * 2 + 0) * HWc + pix];
    const float fyt = cum_flow[(t * 2 + 1) * HWc + pix];
    float acc[Cc];
#pragma unroll
    for (int c = 0; c < Cc; ++c) acc[c] = 0.0f;
    for (int k = 0; k <= t; ++k) {
        const float wkt = mask[t * Lc + k] * __expf(-DECAYc * decay[t * Lc + k]);
        const float fxk = cum_flow[(k * 2 + 0) * HWc + pix];
        const float fyk = cum_flow[(k * 2 + 1) * HWc + pix];
        float gx = base_x + (fxt - fxk);
        const float gy = base_y + (fyt - fyk);
        float m = gx + 1.0f;
        m -= 2.0f * floorf(m * 0.5f);
        gx = m - 1.0f;
        const float ix = (gx + 1.0f) * (Wc * 0.5f) - 0.5f;
        const float iy = (gy + 1.0f) * (Hc * 0.5f) - 0.5f;
        const float x0f = floorf(ix), y0f = floorf(iy);
        const float wx = ix - x0f, wy = iy - y0f;
        const int x0 = (int)x0f, y0 = (int)y0f;
        const int x0r = x0 & (Wc - 1), x1r = (x0 + 1) & (Wc - 1);
        const int y0c = min(max(y0, 0), Hc - 1), y1c = min(max(y0 + 1, 0), Hc - 1);
        const float a00 = wkt * (1.0f - wx) * (1.0f - wy);
        const float a01 = wkt * (1.0f - wx) * wy;
        const float a10 = wkt * wx * (1.0f - wy);
        const float a11 = wkt * wx * wy;
        const int o00 = y0c * Wc + x0r, o01 = y1c * Wc + x0r;
        const int o10 = y0c * Wc + x1r, o11 = y1c * Wc + x1r;
        const float* __restrict__ ik = img + (size_t)k * Cc * HWc;
#pragma unroll
        for (int c = 0; c < Cc; ++c) {
            const float* __restrict__ p = ik + c * HWc;
            acc[c] += p[o00] * a00 + p[o01] * a01 + p[o10] * a10 + p[o11] * a11;
        }
    }
    float* __restrict__ op = out + (size_t)t * Cc * HWc + pix;
#pragma unroll
    for (int c = 0; c < Cc; ++c) op[c * HWc] = acc[c];
}

extern "C" void kernel_launch(void* const* d_in, const int* in_sizes, int n_in,
                              void* d_out, int out_size, void* d_ws, size_t ws_size,
                              hipStream_t stream) {
    const float* img      = (const float*)d_in[0];
    const float* cum_flow = (const float*)d_in[1];
    const float* mask     = (const float*)d_in[2];
    const float* decay    = (const float*)d_in[3];
    float* out = (float*)d_out;

    const size_t needed = (size_t)Lc * HWc * Cc * sizeof(unsigned short);  // 16 MB
    if (ws_size >= needed) {
        unsigned short* imgTb = (unsigned short*)d_ws;
        transpose_cvt_bf16<<<dim3(512), 256, 0, stream>>>(img, imgTb);
        gridsample_bf16_h16b<<<dim3(1024), 256, 0, stream>>>(
            imgTb, cum_flow, mask, decay, img, out);
    } else {
        dim3 grid(Hc, Lc, 1);
        gridsample_warp_acc<<<grid, Wc, 0, stream>>>(img, cum_flow, mask, decay, out);
    }
}